// Round 2
// baseline (8040.411 us; speedup 1.0000x reference)
//
#include <hip/hip_runtime.h>
#include <hip/hip_bf16.h>
#include <cstdint>
#include <cstddef>

#define DI __device__ __forceinline__

DI float bf2f(__hip_bfloat16 h) { return __bfloat162float(h); }

// ---------------------------------------------------------------------------
// dtype sniffer: external tensors are either fp32 or bf16. Inspect the
// `style` buffer (2048 N(0,1) values). Even uint16 positions: if bf16 these
// are real bf16 values (~100% plausible exponent); if fp32 they are low
// mantissa halves (~9% plausible). Majority vote -> flag (1 = fp32).
// Reads stay within min(buffer size) under both hypotheses.
// ---------------------------------------------------------------------------
__global__ void detect_dtype(const unsigned short* __restrict__ raw,
                             int* __restrict__ flag) {
    __shared__ int cnt;
    if (threadIdx.x == 0) cnt = 0;
    __syncthreads();
    int local = 0;
    for (int i = threadIdx.x; i < 1024; i += 256) {
        unsigned short u = raw[2 * i];
        int e = (u >> 7) & 0xFF;               // exponent field (sign dropped)
        if (e >= 110 && e <= 132) local++;     // |x| in ~[2^-17, 2^5]
    }
    atomicAdd(&cnt, local);
    __syncthreads();
    if (threadIdx.x == 0) *flag = (cnt < 512) ? 1 : 0;
}

// ---------------------------------------------------------------------------
// dual-dtype -> fp32 conversion (weights/biases; tiny)
// ---------------------------------------------------------------------------
__global__ void cvt_any_f32(const void* __restrict__ in, float* __restrict__ out,
                            int n, const int* __restrict__ flag) {
    int i = blockIdx.x * blockDim.x + threadIdx.x;
    if (i >= n) return;
    if (*flag) out[i] = ((const float*)in)[i];
    else       out[i] = bf2f(((const __hip_bfloat16*)in)[i]);
}

// ---------------------------------------------------------------------------
// style modulation scales: s[b][o] = style[b,:] . fc_w[o,:] + fc_b[o]
// ---------------------------------------------------------------------------
__global__ void style_mod(const void* __restrict__ style,  // [B,S]
                          const void* __restrict__ fcw,    // [O,S]
                          const void* __restrict__ fcb,    // [O]
                          float* __restrict__ out, int B, int O, int S,
                          const int* __restrict__ flag) {
    int i = blockIdx.x * blockDim.x + threadIdx.x;
    if (i >= B * O) return;
    int b = i / O, o = i - b * O;
    float acc = 0.f;
    if (*flag) {
        const float* sp = (const float*)style + (size_t)b * S;
        const float* wp = (const float*)fcw + (size_t)o * S;
        for (int k = 0; k < S; ++k) acc = fmaf(sp[k], wp[k], acc);
        acc += ((const float*)fcb)[o];
    } else {
        const __hip_bfloat16* sp = (const __hip_bfloat16*)style + (size_t)b * S;
        const __hip_bfloat16* wp = (const __hip_bfloat16*)fcw + (size_t)o * S;
        for (int k = 0; k < S; ++k) acc = fmaf(bf2f(sp[k]), bf2f(wp[k]), acc);
        acc += bf2f(((const __hip_bfloat16*)fcb)[o]);
    }
    out[i] = acc;
}

// ---------------------------------------------------------------------------
// Direct 3x3 conv, stride 1, pad 1, over the virtual tensor
//   concat(p0[C0 ch], p1[C1 ch])  optionally nearest-2x-upsampled (UP).
// D0/D1/DOUT: that pointer is an EXTERNAL tensor whose dtype follows the
// runtime flag (fp32 or bf16); false = our own bf16 workspace tensor.
// EPI: 0 = *scale[b][co]+relu   1 = +bias[co]+relu   2 = +bias[co]
// ---------------------------------------------------------------------------
template<int CIN, int CSPLIT, int H, int W, bool UP, int CO_TILE, int EPI,
         bool D0, bool D1, bool DOUT>
__global__ __launch_bounds__(256)
void conv3x3(const void* __restrict__ p0,
             const void* __restrict__ p1,
             const float* __restrict__ wf,   // [Cout][CIN][3][3] fp32
             const float* __restrict__ sb,   // scale [B][Cout] or bias [Cout]
             void* __restrict__ outv,
             int Cout, const int* __restrict__ flagp) {
    __shared__ float tile[18 * 20];          // 18x18 halo tile, +2 row pad
    constexpr int SH = UP ? H / 2 : H;
    constexpr int SW = UP ? W / 2 : W;
    constexpr int C0 = CSPLIT;
    constexpr int TX = W / 16;

    const int f32 = __builtin_amdgcn_readfirstlane(flagp[0]);
    const int esz0 = (D0 && f32) ? 4 : 2;
    const int esz1 = (D1 && f32) ? 4 : 2;

    const int tid = threadIdx.x;
    const int tx = tid & 15, ty = tid >> 4;
    const int x0 = (blockIdx.x % TX) * 16;
    const int y0 = (blockIdx.x / TX) * 16;
    const int co0 = blockIdx.y * CO_TILE;
    const int b = blockIdx.z;

    const char* bb0 = (const char*)p0 + (size_t)b * C0 * SH * SW * esz0;
    const char* bb1 = (const char*)p1 + (size_t)b * (CIN - C0) * SH * SW * esz1;

    // staging slots: linear idx tid in [0,324); second slot tid+256 if < 324
    int ly1 = tid / 18, lx1 = tid - ly1 * 18;
    int yy1 = y0 - 1 + ly1, xx1 = x0 - 1 + lx1;
    bool in1 = (yy1 >= 0) && (yy1 < H) && (xx1 >= 0) && (xx1 < W);
    int sof1 = in1 ? ((UP ? (yy1 >> 1) : yy1) * SW + (UP ? (xx1 >> 1) : xx1)) : 0;
    float* tp1 = tile + ly1 * 20 + lx1;

    int t2 = tid + 256;
    bool has2 = (t2 < 324);
    int t2c = has2 ? t2 : 0;
    int ly2 = t2c / 18, lx2 = t2c - ly2 * 18;
    int yy2 = y0 - 1 + ly2, xx2 = x0 - 1 + lx2;
    bool in2 = has2 && (yy2 >= 0) && (yy2 < H) && (xx2 >= 0) && (xx2 < W);
    int sof2 = in2 ? ((UP ? (yy2 >> 1) : yy2) * SW + (UP ? (xx2 >> 1) : xx2)) : 0;
    float* tp2 = tile + ly2 * 20 + lx2;

    float acc[CO_TILE];
#pragma unroll
    for (int j = 0; j < CO_TILE; ++j) acc[j] = 0.f;

    const float* wbase = wf + (size_t)co0 * CIN * 9;

    for (int ci = 0; ci < CIN; ++ci) {
        bool isP0 = (ci < C0);
        const char* src = isP0 ? bb0 + (size_t)ci * SH * SW * esz0
                               : bb1 + (size_t)(ci - C0) * SH * SW * esz1;
        bool sf = isP0 ? (D0 && f32) : (D1 && f32);
        __syncthreads();
        float v1 = 0.f, v2 = 0.f;
        if (sf) {
            if (in1) v1 = ((const float*)src)[sof1];
            if (in2) v2 = ((const float*)src)[sof2];
        } else {
            if (in1) v1 = bf2f(((const __hip_bfloat16*)src)[sof1]);
            if (in2) v2 = bf2f(((const __hip_bfloat16*)src)[sof2]);
        }
        tp1[0] = v1;
        if (has2) tp2[0] = v2;
        __syncthreads();

        float v[9];
#pragma unroll
        for (int r = 0; r < 3; ++r)
#pragma unroll
            for (int c = 0; c < 3; ++c)
                v[r * 3 + c] = tile[(ty + r) * 20 + tx + c];

        const float* wp = wbase + ci * 9;
#pragma unroll
        for (int j = 0; j < CO_TILE; ++j) {
            const float* w9 = wp + (size_t)j * CIN * 9;  // uniform -> s_load
#pragma unroll
            for (int k = 0; k < 9; ++k)
                acc[j] = fmaf(v[k], w9[k], acc[j]);
        }
    }

    const int oy = y0 + ty, ox = x0 + tx;
#pragma unroll
    for (int j = 0; j < CO_TILE; ++j) {
        const int co = co0 + j;
        float val = acc[j];
        if (EPI == 0)      val = fmaxf(val * sb[b * Cout + co], 0.f);
        else if (EPI == 1) val = fmaxf(val + sb[co], 0.f);
        else               val = val + sb[co];
        size_t oidx = (((size_t)b * Cout + co) * H + oy) * W + ox;
        if (DOUT && f32) ((float*)outv)[oidx] = val;
        else ((__hip_bfloat16*)outv)[oidx] = __float2bfloat16(val);
    }
}

// ---------------------------------------------------------------------------
// Launch
// ---------------------------------------------------------------------------
extern "C" void kernel_launch(void* const* d_in, const int* in_sizes, int n_in,
                              void* d_out, int out_size, void* d_ws, size_t ws_size,
                              hipStream_t stream) {
    const void* x     = d_in[0];   // [8,256,64,64]
    const void* enc1  = d_in[1];   // [8,64,256,256]
    const void* enc2  = d_in[2];   // [8,128,128,128]
    const void* enc3  = d_in[3];   // [8,256,64,64]
    const void* style = d_in[4];   // [8,256]
    const void* w1    = d_in[5];   // [128,512,3,3]
    const void* fcw1  = d_in[6];   // [128,256]
    const void* fcb1  = d_in[7];   // [128]
    const void* w2    = d_in[8];   // [64,256,3,3]
    const void* fcw2  = d_in[9];   // [64,256]
    const void* fcb2  = d_in[10];  // [64]
    const void* fw1   = d_in[11];  // [64,128,3,3]
    const void* fb1   = d_in[12];  // [64]
    const void* fw2   = d_in[13];  // [3,64,3,3]
    const void* fb2   = d_in[14];  // [3]
    char* ws = (char*)d_ws;

    // workspace layout (bytes):
    //   [0, ~3.3MB)   fp32 weights + scales + biases + dtype flag
    //   [4MB, 71MB)   h3 (bf16, 67MB); h1 (bf16, 33.5MB) aliases its head
    //   [71MB, 138MB) h2 (bf16, 67MB)
    float* w1f  = (float*)(ws + 0);         // 589824 floats
    float* w2f  = (float*)(ws + 2359296);   // 147456
    float* fw1f = (float*)(ws + 2949120);   // 73728
    float* fw2f = (float*)(ws + 3244032);   // 1728
    float* s1   = (float*)(ws + 3250944);   // 1024
    float* s2   = (float*)(ws + 3255040);   // 512
    float* fb1f = (float*)(ws + 3257088);   // 64
    float* fb2f = (float*)(ws + 3257344);   // 3
    int*   flag = (int*)(ws + 3257360);
    __hip_bfloat16* h1 = (__hip_bfloat16*)(ws + (size_t)(4u << 20));
    __hip_bfloat16* h3 = (__hip_bfloat16*)(ws + (size_t)(4u << 20));
    __hip_bfloat16* h2 = (__hip_bfloat16*)(ws + (size_t)(4u << 20) + 67108864u);

    hipLaunchKernelGGL(detect_dtype, dim3(1), dim3(256), 0, stream,
                       (const unsigned short*)style, flag);

    auto gb = [](int n) { return (n + 255) / 256; };
    hipLaunchKernelGGL(cvt_any_f32, dim3(gb(589824)), dim3(256), 0, stream, w1, w1f, 589824, flag);
    hipLaunchKernelGGL(cvt_any_f32, dim3(gb(147456)), dim3(256), 0, stream, w2, w2f, 147456, flag);
    hipLaunchKernelGGL(cvt_any_f32, dim3(gb(73728)),  dim3(256), 0, stream, fw1, fw1f, 73728, flag);
    hipLaunchKernelGGL(cvt_any_f32, dim3(gb(1728)),   dim3(256), 0, stream, fw2, fw2f, 1728, flag);
    hipLaunchKernelGGL(cvt_any_f32, dim3(1), dim3(256), 0, stream, fb1, fb1f, 64, flag);
    hipLaunchKernelGGL(cvt_any_f32, dim3(1), dim3(256), 0, stream, fb2, fb2f, 3, flag);

    hipLaunchKernelGGL(style_mod, dim3(4), dim3(256), 0, stream, style, fcw1, fcb1, s1, 8, 128, 256, flag);
    hipLaunchKernelGGL(style_mod, dim3(2), dim3(256), 0, stream, style, fcw2, fcb2, s2, 8, 64, 256, flag);

    // L1: up2(concat(x, enc3)) [512ch,128x128] -> h1 [128ch,128x128], *s1, relu
    hipLaunchKernelGGL((conv3x3<512, 256, 128, 128, true, 8, 0, true, true, false>),
                       dim3(64, 16, 8), dim3(256), 0, stream,
                       x, enc3, w1f, s1, h1, 128, flag);
    // L2: up2(concat(h1, enc2)) [256ch,256x256] -> h2 [64ch,256x256], *s2, relu
    hipLaunchKernelGGL((conv3x3<256, 128, 256, 256, true, 8, 0, false, true, false>),
                       dim3(256, 8, 8), dim3(256), 0, stream,
                       h1, enc2, w2f, s2, h2, 64, flag);
    // L3: concat(h2, enc1) [128ch,256x256] -> h3 [64ch,256x256], +fb1, relu
    hipLaunchKernelGGL((conv3x3<128, 64, 256, 256, false, 8, 1, false, true, false>),
                       dim3(256, 8, 8), dim3(256), 0, stream,
                       h2, enc1, fw1f, fb1f, h3, 64, flag);
    // L4: h3 [64ch,256x256] -> out [3ch,256x256], +fb2
    hipLaunchKernelGGL((conv3x3<64, 64, 256, 256, false, 3, 2, false, false, true>),
                       dim3(256, 1, 8), dim3(256), 0, stream,
                       h3, h3, fw2f, fb2f, d_out, 3, flag);
}

// Round 3
// 1224.900 us; speedup vs baseline: 6.5641x; 6.5641x over previous
//
#include <hip/hip_runtime.h>
#include <hip/hip_bf16.h>
#include <cstdint>
#include <cstddef>

typedef short short8 __attribute__((ext_vector_type(8)));
typedef unsigned short ushort8 __attribute__((ext_vector_type(8)));
typedef float f32x4 __attribute__((ext_vector_type(4)));

#define DI __device__ __forceinline__

DI float bf2f(__hip_bfloat16 h) { return __bfloat162float(h); }
DI unsigned short f2bf(float f) {
    __hip_bfloat16 h = __float2bfloat16(f);
    return *(unsigned short*)&h;
}

constexpr int cilog2(int v) { int r = 0; while (v > 1) { v >>= 1; ++r; } return r; }

// ---------------------------------------------------------------------------
// dtype sniffer (1 = fp32 external tensors, 0 = bf16)
// ---------------------------------------------------------------------------
__global__ void detect_dtype(const unsigned short* __restrict__ raw,
                             int* __restrict__ flag) {
    __shared__ int cnt;
    if (threadIdx.x == 0) cnt = 0;
    __syncthreads();
    int local = 0;
    for (int i = threadIdx.x; i < 1024; i += 256) {
        unsigned short u = raw[2 * i];
        int e = (u >> 7) & 0xFF;
        if (e >= 110 && e <= 132) local++;
    }
    atomicAdd(&cnt, local);
    __syncthreads();
    if (threadIdx.x == 0) *flag = (cnt < 512) ? 1 : 0;
}

// ---------------------------------------------------------------------------
// dual-dtype -> fp32, with zero-padding to npad
// ---------------------------------------------------------------------------
__global__ void cvt_pad_f32(const void* __restrict__ in, float* __restrict__ out,
                            int n, int npad, const int* __restrict__ flag) {
    int i = blockIdx.x * blockDim.x + threadIdx.x;
    if (i >= npad) return;
    float v = 0.f;
    if (i < n) v = (*flag) ? ((const float*)in)[i] : bf2f(((const __hip_bfloat16*)in)[i]);
    out[i] = v;
}

// ---------------------------------------------------------------------------
// style modulation scales
// ---------------------------------------------------------------------------
__global__ void style_mod(const void* __restrict__ style, const void* __restrict__ fcw,
                          const void* __restrict__ fcb, float* __restrict__ out,
                          int B, int O, int S, const int* __restrict__ flag) {
    int i = blockIdx.x * blockDim.x + threadIdx.x;
    if (i >= B * O) return;
    int b = i / O, o = i - b * O;
    float acc = 0.f;
    if (*flag) {
        const float* sp = (const float*)style + (size_t)b * S;
        const float* wp = (const float*)fcw + (size_t)o * S;
        for (int k = 0; k < S; ++k) acc = fmaf(sp[k], wp[k], acc);
        acc += ((const float*)fcb)[o];
    } else {
        const __hip_bfloat16* sp = (const __hip_bfloat16*)style + (size_t)b * S;
        const __hip_bfloat16* wp = (const __hip_bfloat16*)fcw + (size_t)o * S;
        for (int k = 0; k < S; ++k) acc = fmaf(bf2f(sp[k]), bf2f(wp[k]), acc);
        acc += bf2f(((const __hip_bfloat16*)fcb)[o]);
    }
    out[i] = acc;
}

// ---------------------------------------------------------------------------
// NCHW (flag dtype) -> NHWC bf16 into a channel slot [coff, coff+C) of a
// CT-stride destination. Block: 64 pixels x 32 channels via LDS transpose.
// ---------------------------------------------------------------------------
__global__ __launch_bounds__(256)
void nchw_to_nhwc(const void* __restrict__ in, unsigned short* __restrict__ out,
                  int C, int HW, int CT, int coff, const int* __restrict__ flag) {
    __shared__ float t[32][65];
    const int f32 = flag[0];
    const int pbase = blockIdx.x * 64;
    const int cbase = blockIdx.y * 32;
    const int b = blockIdx.z;
    const size_t ibase = ((size_t)b * C + cbase) * HW + pbase;
#pragma unroll
    for (int i = 0; i < 8; ++i) {
        int e = threadIdx.x + i * 256;       // 0..2047
        int c = e >> 6, p = e & 63;          // coalesced along p
        size_t idx = ibase + (size_t)c * HW + p;
        float v = f32 ? ((const float*)in)[idx] : bf2f(((const __hip_bfloat16*)in)[idx]);
        t[c][p] = v;
    }
    __syncthreads();
#pragma unroll
    for (int i = 0; i < 8; ++i) {
        int e = threadIdx.x + i * 256;
        int p = e >> 5, c = e & 31;          // coalesced along c
        out[((size_t)b * HW + pbase + p) * CT + coff + cbase + c] = f2bf(t[c][p]);
    }
}

// ---------------------------------------------------------------------------
// Pack conv weights [Cout][CIN][3][3] (flag dtype) into MFMA B-fragment
// order: pkw[tap][kc][nc][lane][8] bf16, k = kc*32 + (lane>>4)*8 + j,
// n = nc*16 + (lane&15). n >= Creal -> 0 (padding for L4).
// ---------------------------------------------------------------------------
__global__ __launch_bounds__(256)
void pack_w(const void* __restrict__ w, unsigned short* __restrict__ pkw,
            int Creal, int CIN, int NC, int KC, const int* __restrict__ flag) {
    int gid = blockIdx.x * 256 + threadIdx.x;
    int total = 9 * KC * NC * 64;
    if (gid >= total) return;
    const int f32 = flag[0];
    int lane = gid & 63; int q = gid >> 6;
    int nc = q % NC; q /= NC; int kc = q % KC; int tap = q / KC;
    int lm = lane & 15, lk = lane >> 4;
    int n = nc * 16 + lm;
    int kh = tap / 3, kw = tap - kh * 3;
    ushort8 v;
#pragma unroll
    for (int j = 0; j < 8; ++j) {
        int k = kc * 32 + lk * 8 + j;
        float f = 0.f;
        if (n < Creal) {
            size_t si = (((size_t)n * CIN + k) * 3 + kh) * 3 + kw;
            f = f32 ? ((const float*)w)[si] : bf2f(((const __hip_bfloat16*)w)[si]);
        }
        v[j] = f2bf(f);
    }
    *(ushort8*)(pkw + (size_t)gid * 8) = v;
}

// ---------------------------------------------------------------------------
// MFMA implicit-GEMM 3x3 conv, NHWC bf16 input (CT channel stride), stride 1
// pad 1, optional fused nearest-2x upsample of the input (UP).
//   M = flat pixels (256/block, 64/wave as 4 m-tiles of 16)
//   N = NT*16 output channels/block (nco0 = blockIdx.y*NT)
//   K = 9 taps x CT, chunked 32; weights staged per tap into LDS.
// EPI: 0 = *scale[b][co]+relu (NHWC out)  1 = +bias[co]+relu (NHWC out)
//      2 = +bias[co], external NCHW store with flag dtype (Cout=3)
// ---------------------------------------------------------------------------
template<int CT, int H, int W, bool UP, int NT, int NC, int KCS, int EPI, int CTO>
__global__ __launch_bounds__(256)
void conv_mfma(const unsigned short* __restrict__ in,
               const unsigned short* __restrict__ pkw,
               const float* __restrict__ sb,
               void* __restrict__ outv,
               const int* __restrict__ flagp) {
    constexpr int KC = CT / 32;
    constexpr int HW = H * W;
    constexpr int LHW = cilog2(HW);
    constexpr int LW = cilog2(W);
    constexpr int SW = UP ? W / 2 : W;
    constexpr int SH = UP ? H / 2 : H;
    constexpr int STAGES = KC / KCS;
    __shared__ __align__(16) unsigned short lds[KCS * NT * 512];  // KCS*NT KB

    const int tid = threadIdx.x;
    const int wave = tid >> 6, lane = tid & 63;
    const int lm = lane & 15, lk = lane >> 4;
    const int blkm = blockIdx.x * 256;
    const int nco0 = blockIdx.y * NT;

    int pb[4], py[4], px[4];
#pragma unroll
    for (int t = 0; t < 4; ++t) {
        int P = blkm + wave * 64 + t * 16 + lm;
        pb[t] = P >> LHW;
        int rem = P & (HW - 1);
        py[t] = rem >> LW;
        px[t] = rem & (W - 1);
    }

    f32x4 acc[4][NT];
#pragma unroll
    for (int t = 0; t < 4; ++t)
#pragma unroll
        for (int u = 0; u < NT; ++u)
            acc[t][u] = f32x4{0.f, 0.f, 0.f, 0.f};

    for (int tap = 0; tap < 9; ++tap) {
        const int dy = tap / 3 - 1, dx = tap - (tap / 3) * 3 - 1;
        int ab[4]; bool av[4];
#pragma unroll
        for (int t = 0; t < 4; ++t) {
            int ty = py[t] + dy, tx = px[t] + dx;
            av[t] = (ty >= 0) && (ty < H) && (tx >= 0) && (tx < W);
            int iy = UP ? (ty >> 1) : ty;
            int ix = UP ? (tx >> 1) : tx;
            iy = av[t] ? iy : 0; ix = av[t] ? ix : 0;
            ab[t] = (((pb[t] * SH + iy) * SW + ix) * CT + lk * 8) * 2;  // bytes
        }
        for (int st = 0; st < STAGES; ++st) {
            const int kc0 = st * KCS;
            __syncthreads();
            {   // stage KCS*NT KB of B-fragments into LDS
                constexpr int T16 = KCS * NT * 64;   // 16B units
                const char* pwb = (const char*)pkw;
                for (int f = tid; f < T16; f += 256) {
                    int fb = f * 16;
                    int kcl = fb / (NT * 1024);
                    int rem2 = fb - kcl * (NT * 1024);
                    int soff = ((tap * KC + kc0 + kcl) * NC + nco0) * 1024 + rem2;
                    uint4 v = *(const uint4*)(pwb + soff);
                    *(uint4*)((char*)lds + fb) = v;
                }
            }
            __syncthreads();
#pragma unroll 4
            for (int kcl = 0; kcl < KCS; ++kcl) {
                short8 a[4];
#pragma unroll
                for (int t = 0; t < 4; ++t) {
                    uint4 raw = *(const uint4*)((const char*)in + (ab[t] + (kc0 + kcl) * 64));
                    uint4 z = uint4{0u, 0u, 0u, 0u};
                    uint4 sel = av[t] ? raw : z;
                    a[t] = *(short8*)&sel;
                }
#pragma unroll
                for (int u = 0; u < NT; ++u) {
                    short8 bfr = *(short8*)((char*)lds + (kcl * NT + u) * 1024 + lane * 16);
#pragma unroll
                    for (int t = 0; t < 4; ++t)
                        acc[t][u] = __builtin_amdgcn_mfma_f32_16x16x32_bf16(
                            a[t], bfr, acc[t][u], 0, 0, 0);
                }
            }
        }
    }

    // epilogue: D lane mapping col = lane&15, row = (lane>>4)*4 + r  [m89]
    const int b_blk = blkm >> LHW;
    if constexpr (EPI == 0 || EPI == 1) {
        unsigned short* outp = (unsigned short*)outv;
#pragma unroll
        for (int u = 0; u < NT; ++u) {
            const int co = nco0 * 16 + u * 16 + lm;
            const float s = (EPI == 0) ? sb[b_blk * (NC * 16) + co] : sb[co];
#pragma unroll
            for (int t = 0; t < 4; ++t) {
                const int Pb = blkm + wave * 64 + t * 16 + lk * 4;
#pragma unroll
                for (int r = 0; r < 4; ++r) {
                    float v = acc[t][u][r];
                    v = (EPI == 0) ? v * s : v + s;
                    v = fmaxf(v, 0.f);
                    outp[(size_t)(Pb + r) * CTO + co] = f2bf(v);
                }
            }
        }
    } else {
        const int f32o = flagp[0];
        const int co = lm;                    // NT == 1
        if (co < 3) {
            const float bias = sb[co];
#pragma unroll
            for (int t = 0; t < 4; ++t) {
                const int Pb = blkm + wave * 64 + t * 16 + lk * 4;
#pragma unroll
                for (int r = 0; r < 4; ++r) {
                    const int P = Pb + r;
                    const int b = P >> LHW;
                    const int rem = P & (HW - 1);
                    const float v = acc[t][0][r] + bias;
                    const int oi = (b * 3 + co) * HW + rem;
                    if (f32o) ((float*)outv)[oi] = v;
                    else ((unsigned short*)outv)[oi] = f2bf(v);
                }
            }
        }
    }
}

// ===========================================================================
// FALLBACK (round-2 proven path) — used only if ws_size is too small
// ===========================================================================
template<int CIN, int CSPLIT, int H, int W, bool UP, int CO_TILE, int EPI,
         bool D0, bool D1, bool DOUT>
__global__ __launch_bounds__(256)
void conv3x3(const void* __restrict__ p0, const void* __restrict__ p1,
             const float* __restrict__ wf, const float* __restrict__ sb,
             void* __restrict__ outv, int Cout, const int* __restrict__ flagp) {
    __shared__ float tile[18 * 20];
    constexpr int SH = UP ? H / 2 : H;
    constexpr int SW = UP ? W / 2 : W;
    constexpr int C0 = CSPLIT;
    constexpr int TX = W / 16;

    const int f32 = __builtin_amdgcn_readfirstlane(flagp[0]);
    const int esz0 = (D0 && f32) ? 4 : 2;
    const int esz1 = (D1 && f32) ? 4 : 2;

    const int tid = threadIdx.x;
    const int tx = tid & 15, ty = tid >> 4;
    const int x0 = (blockIdx.x % TX) * 16;
    const int y0 = (blockIdx.x / TX) * 16;
    const int co0 = blockIdx.y * CO_TILE;
    const int b = blockIdx.z;

    const char* bb0 = (const char*)p0 + (size_t)b * C0 * SH * SW * esz0;
    const char* bb1 = (const char*)p1 + (size_t)b * (CIN - C0) * SH * SW * esz1;

    int ly1 = tid / 18, lx1 = tid - ly1 * 18;
    int yy1 = y0 - 1 + ly1, xx1 = x0 - 1 + lx1;
    bool in1 = (yy1 >= 0) && (yy1 < H) && (xx1 >= 0) && (xx1 < W);
    int sof1 = in1 ? ((UP ? (yy1 >> 1) : yy1) * SW + (UP ? (xx1 >> 1) : xx1)) : 0;
    float* tp1 = tile + ly1 * 20 + lx1;

    int t2 = tid + 256;
    bool has2 = (t2 < 324);
    int t2c = has2 ? t2 : 0;
    int ly2 = t2c / 18, lx2 = t2c - ly2 * 18;
    int yy2 = y0 - 1 + ly2, xx2 = x0 - 1 + lx2;
    bool in2 = has2 && (yy2 >= 0) && (yy2 < H) && (xx2 >= 0) && (xx2 < W);
    int sof2 = in2 ? ((UP ? (yy2 >> 1) : yy2) * SW + (UP ? (xx2 >> 1) : xx2)) : 0;
    float* tp2 = tile + ly2 * 20 + lx2;

    float acc[CO_TILE];
#pragma unroll
    for (int j = 0; j < CO_TILE; ++j) acc[j] = 0.f;
    const float* wbase = wf + (size_t)co0 * CIN * 9;

    for (int ci = 0; ci < CIN; ++ci) {
        bool isP0 = (ci < C0);
        const char* src = isP0 ? bb0 + (size_t)ci * SH * SW * esz0
                               : bb1 + (size_t)(ci - C0) * SH * SW * esz1;
        bool sf = isP0 ? (D0 && f32) : (D1 && f32);
        __syncthreads();
        float v1 = 0.f, v2 = 0.f;
        if (sf) {
            if (in1) v1 = ((const float*)src)[sof1];
            if (in2) v2 = ((const float*)src)[sof2];
        } else {
            if (in1) v1 = bf2f(((const __hip_bfloat16*)src)[sof1]);
            if (in2) v2 = bf2f(((const __hip_bfloat16*)src)[sof2]);
        }
        tp1[0] = v1;
        if (has2) tp2[0] = v2;
        __syncthreads();

        float v[9];
#pragma unroll
        for (int r = 0; r < 3; ++r)
#pragma unroll
            for (int c = 0; c < 3; ++c)
                v[r * 3 + c] = tile[(ty + r) * 20 + tx + c];

        const float* wp = wbase + ci * 9;
#pragma unroll
        for (int j = 0; j < CO_TILE; ++j) {
            const float* w9 = wp + (size_t)j * CIN * 9;
#pragma unroll
            for (int k = 0; k < 9; ++k)
                acc[j] = fmaf(v[k], w9[k], acc[j]);
        }
    }

    const int oy = y0 + ty, ox = x0 + tx;
#pragma unroll
    for (int j = 0; j < CO_TILE; ++j) {
        const int co = co0 + j;
        float val = acc[j];
        if (EPI == 0)      val = fmaxf(val * sb[b * Cout + co], 0.f);
        else if (EPI == 1) val = fmaxf(val + sb[co], 0.f);
        else               val = val + sb[co];
        size_t oidx = (((size_t)b * Cout + co) * H + oy) * W + ox;
        if (DOUT && f32) ((float*)outv)[oidx] = val;
        else ((__hip_bfloat16*)outv)[oidx] = __float2bfloat16(val);
    }
}

// ---------------------------------------------------------------------------
// Launch
// ---------------------------------------------------------------------------
extern "C" void kernel_launch(void* const* d_in, const int* in_sizes, int n_in,
                              void* d_out, int out_size, void* d_ws, size_t ws_size,
                              hipStream_t stream) {
    const void* x     = d_in[0];   const void* enc1  = d_in[1];
    const void* enc2  = d_in[2];   const void* enc3  = d_in[3];
    const void* style = d_in[4];
    const void* w1    = d_in[5];   const void* fcw1  = d_in[6];  const void* fcb1 = d_in[7];
    const void* w2    = d_in[8];   const void* fcw2  = d_in[9];  const void* fcb2 = d_in[10];
    const void* fw1   = d_in[11];  const void* fb1   = d_in[12];
    const void* fw2   = d_in[13];  const void* fb2   = d_in[14];
    char* ws = (char*)d_ws;
    auto gb = [](int n) { return (n + 255) / 256; };

    constexpr size_t REQ = 272629760ULL;  // 4MB + 67MB + 67MB + 134MB

    if (ws_size >= REQ) {
        // ---- fast path (MFMA implicit GEMM, NHWC) ----
        unsigned short* pkw1 = (unsigned short*)(ws + 0);        // 1,179,648 B
        unsigned short* pkw2 = (unsigned short*)(ws + 1179648);  //   294,912
        unsigned short* pkw3 = (unsigned short*)(ws + 1474560);  //   147,456
        unsigned short* pkw4 = (unsigned short*)(ws + 1622016);  //    18,432
        float* s1    = (float*)(ws + 1640448);
        float* s2    = (float*)(ws + 1644544);
        float* fb1f  = (float*)(ws + 1646592);
        float* fb2f  = (float*)(ws + 1646848);
        int*   flag  = (int*)(ws + 1646912);
        unsigned short* buf0 = (unsigned short*)(ws + (4u << 20));              // 33.5MB [B,64,64,512]
        unsigned short* h3   = (unsigned short*)(ws + (4u << 20));              // 67MB   [B,256,256,64] (after buf0 dies)
        unsigned short* buf1 = (unsigned short*)(ws + (4u << 20) + 67108864u);  // 67MB   [B,128,128,256]
        unsigned short* buf2 = (unsigned short*)(ws + (4u << 20) + 134217728u); // 134MB  [B,256,256,128]

        hipLaunchKernelGGL(detect_dtype, dim3(1), dim3(256), 0, stream,
                           (const unsigned short*)style, flag);

        // transposes into concat slots
        hipLaunchKernelGGL(nchw_to_nhwc, dim3(64, 8, 8),   dim3(256), 0, stream, x,    buf0, 256, 4096,  512, 0,   flag);
        hipLaunchKernelGGL(nchw_to_nhwc, dim3(64, 8, 8),   dim3(256), 0, stream, enc3, buf0, 256, 4096,  512, 256, flag);
        hipLaunchKernelGGL(nchw_to_nhwc, dim3(256, 4, 8),  dim3(256), 0, stream, enc2, buf1, 128, 16384, 256, 128, flag);
        hipLaunchKernelGGL(nchw_to_nhwc, dim3(1024, 2, 8), dim3(256), 0, stream, enc1, buf2, 64,  65536, 128, 64,  flag);

        // weight packing
        hipLaunchKernelGGL(pack_w, dim3(gb(73728)), dim3(256), 0, stream, w1,  pkw1, 128, 512, 8, 16, flag);
        hipLaunchKernelGGL(pack_w, dim3(gb(18432)), dim3(256), 0, stream, w2,  pkw2, 64,  256, 4, 8,  flag);
        hipLaunchKernelGGL(pack_w, dim3(gb(9216)),  dim3(256), 0, stream, fw1, pkw3, 64,  128, 4, 4,  flag);
        hipLaunchKernelGGL(pack_w, dim3(gb(1152)),  dim3(256), 0, stream, fw2, pkw4, 3,   64,  1, 2,  flag);

        hipLaunchKernelGGL(style_mod, dim3(4), dim3(256), 0, stream, style, fcw1, fcb1, s1, 8, 128, 256, flag);
        hipLaunchKernelGGL(style_mod, dim3(2), dim3(256), 0, stream, style, fcw2, fcb2, s2, 8, 64, 256, flag);
        hipLaunchKernelGGL(cvt_pad_f32, dim3(1), dim3(256), 0, stream, fb1, fb1f, 64, 64, flag);
        hipLaunchKernelGGL(cvt_pad_f32, dim3(1), dim3(256), 0, stream, fb2, fb2f, 3, 16, flag);

        // L1: buf0 [B,64,64,512] -up2-> buf1 ch0-127 [B,128,128,(256)]
        hipLaunchKernelGGL((conv_mfma<512, 128, 128, true, 4, 8, 8, 0, 256>),
                           dim3(512, 2), dim3(256), 0, stream, buf0, pkw1, s1, buf1, flag);
        // L2: buf1 [B,128,128,256] -up2-> buf2 ch0-63 [B,256,256,(128)]
        hipLaunchKernelGGL((conv_mfma<256, 256, 256, true, 4, 4, 8, 0, 128>),
                           dim3(2048, 1), dim3(256), 0, stream, buf1, pkw2, s2, buf2, flag);
        // L3: buf2 [B,256,256,128] -> h3 [B,256,256,64]
        hipLaunchKernelGGL((conv_mfma<128, 256, 256, false, 4, 4, 4, 1, 64>),
                           dim3(2048, 1), dim3(256), 0, stream, buf2, pkw3, fb1f, h3, flag);
        // L4: h3 -> d_out NCHW [B,3,256,256] (external dtype)
        hipLaunchKernelGGL((conv_mfma<64, 256, 256, false, 1, 1, 2, 2, 0>),
                           dim3(2048, 1), dim3(256), 0, stream, h3, pkw4, fb2f, d_out, flag);
        return;
    }

    // ---- fallback: round-2 direct conv path ----
    float* w1f  = (float*)(ws + 0);
    float* w2f  = (float*)(ws + 2359296);
    float* fw1f = (float*)(ws + 2949120);
    float* fw2f = (float*)(ws + 3244032);
    float* s1   = (float*)(ws + 3250944);
    float* s2   = (float*)(ws + 3255040);
    float* fb1f = (float*)(ws + 3257088);
    float* fb2f = (float*)(ws + 3257344);
    int*   flag = (int*)(ws + 3257360);
    __hip_bfloat16* h1 = (__hip_bfloat16*)(ws + (size_t)(4u << 20));
    __hip_bfloat16* h3 = (__hip_bfloat16*)(ws + (size_t)(4u << 20));
    __hip_bfloat16* h2 = (__hip_bfloat16*)(ws + (size_t)(4u << 20) + 67108864u);

    hipLaunchKernelGGL(detect_dtype, dim3(1), dim3(256), 0, stream,
                       (const unsigned short*)style, flag);
    hipLaunchKernelGGL(cvt_pad_f32, dim3(gb(589824)), dim3(256), 0, stream, w1, w1f, 589824, 589824, flag);
    hipLaunchKernelGGL(cvt_pad_f32, dim3(gb(147456)), dim3(256), 0, stream, w2, w2f, 147456, 147456, flag);
    hipLaunchKernelGGL(cvt_pad_f32, dim3(gb(73728)),  dim3(256), 0, stream, fw1, fw1f, 73728, 73728, flag);
    hipLaunchKernelGGL(cvt_pad_f32, dim3(gb(1728)),   dim3(256), 0, stream, fw2, fw2f, 1728, 1728, flag);
    hipLaunchKernelGGL(cvt_pad_f32, dim3(1), dim3(256), 0, stream, fb1, fb1f, 64, 64, flag);
    hipLaunchKernelGGL(cvt_pad_f32, dim3(1), dim3(256), 0, stream, fb2, fb2f, 3, 3, flag);
    hipLaunchKernelGGL(style_mod, dim3(4), dim3(256), 0, stream, style, fcw1, fcb1, s1, 8, 128, 256, flag);
    hipLaunchKernelGGL(style_mod, dim3(2), dim3(256), 0, stream, style, fcw2, fcb2, s2, 8, 64, 256, flag);

    hipLaunchKernelGGL((conv3x3<512, 256, 128, 128, true, 8, 0, true, true, false>),
                       dim3(64, 16, 8), dim3(256), 0, stream, x, enc3, w1f, s1, h1, 128, flag);
    hipLaunchKernelGGL((conv3x3<256, 128, 256, 256, true, 8, 0, false, true, false>),
                       dim3(256, 8, 8), dim3(256), 0, stream, h1, enc2, w2f, s2, h2, 64, flag);
    hipLaunchKernelGGL((conv3x3<128, 64, 256, 256, false, 8, 1, false, true, false>),
                       dim3(256, 8, 8), dim3(256), 0, stream, h2, enc1, fw1f, fb1f, h3, 64, flag);
    hipLaunchKernelGGL((conv3x3<64, 64, 256, 256, false, 3, 2, false, false, true>),
                       dim3(256, 1, 8), dim3(256), 0, stream, h3, h3, fw2f, fb2f, d_out, 3, flag);
}

// Round 4
// 912.001 us; speedup vs baseline: 8.8162x; 1.3431x over previous
//
#include <hip/hip_runtime.h>
#include <hip/hip_bf16.h>
#include <cstdint>
#include <cstddef>

typedef short short8 __attribute__((ext_vector_type(8)));
typedef unsigned short ushort8 __attribute__((ext_vector_type(8)));
typedef float f32x4 __attribute__((ext_vector_type(4)));

#define DI __device__ __forceinline__

DI float bf2f(__hip_bfloat16 h) { return __bfloat162float(h); }
DI unsigned short f2bf(float f) {
    __hip_bfloat16 h = __float2bfloat16(f);
    return *(unsigned short*)&h;
}

constexpr int cilog2(int v) { int r = 0; while (v > 1) { v >>= 1; ++r; } return r; }

// ---------------------------------------------------------------------------
// dtype sniffer (1 = fp32 external tensors, 0 = bf16)
// ---------------------------------------------------------------------------
__global__ void detect_dtype(const unsigned short* __restrict__ raw,
                             int* __restrict__ flag) {
    __shared__ int cnt;
    if (threadIdx.x == 0) cnt = 0;
    __syncthreads();
    int local = 0;
    for (int i = threadIdx.x; i < 1024; i += 256) {
        unsigned short u = raw[2 * i];
        int e = (u >> 7) & 0xFF;
        if (e >= 110 && e <= 132) local++;
    }
    atomicAdd(&cnt, local);
    __syncthreads();
    if (threadIdx.x == 0) *flag = (cnt < 512) ? 1 : 0;
}

// ---------------------------------------------------------------------------
// dual-dtype -> fp32, zero-padded to npad
// ---------------------------------------------------------------------------
__global__ void cvt_pad_f32(const void* __restrict__ in, float* __restrict__ out,
                            int n, int npad, const int* __restrict__ flag) {
    int i = blockIdx.x * blockDim.x + threadIdx.x;
    if (i >= npad) return;
    float v = 0.f;
    if (i < n) v = (*flag) ? ((const float*)in)[i] : bf2f(((const __hip_bfloat16*)in)[i]);
    out[i] = v;
}

// ---------------------------------------------------------------------------
// style modulation scales
// ---------------------------------------------------------------------------
__global__ void style_mod(const void* __restrict__ style, const void* __restrict__ fcw,
                          const void* __restrict__ fcb, float* __restrict__ out,
                          int B, int O, int S, const int* __restrict__ flag) {
    int i = blockIdx.x * blockDim.x + threadIdx.x;
    if (i >= B * O) return;
    int b = i / O, o = i - b * O;
    float acc = 0.f;
    if (*flag) {
        const float* sp = (const float*)style + (size_t)b * S;
        const float* wp = (const float*)fcw + (size_t)o * S;
        for (int k = 0; k < S; ++k) acc = fmaf(sp[k], wp[k], acc);
        acc += ((const float*)fcb)[o];
    } else {
        const __hip_bfloat16* sp = (const __hip_bfloat16*)style + (size_t)b * S;
        const __hip_bfloat16* wp = (const __hip_bfloat16*)fcw + (size_t)o * S;
        for (int k = 0; k < S; ++k) acc = fmaf(bf2f(sp[k]), bf2f(wp[k]), acc);
        acc += bf2f(((const __hip_bfloat16*)fcb)[o]);
    }
    out[i] = acc;
}

// ---------------------------------------------------------------------------
// NCHW (flag dtype) -> NHWC bf16 into channel slot [coff, coff+C)
// ---------------------------------------------------------------------------
__global__ __launch_bounds__(256)
void nchw_to_nhwc(const void* __restrict__ in, unsigned short* __restrict__ out,
                  int C, int HW, int CT, int coff, const int* __restrict__ flag) {
    __shared__ float t[32][65];
    const int f32 = flag[0];
    const int pbase = blockIdx.x * 64;
    const int cbase = blockIdx.y * 32;
    const int b = blockIdx.z;
    const size_t ibase = ((size_t)b * C + cbase) * HW + pbase;
#pragma unroll
    for (int i = 0; i < 8; ++i) {
        int e = threadIdx.x + i * 256;
        int c = e >> 6, p = e & 63;
        size_t idx = ibase + (size_t)c * HW + p;
        float v = f32 ? ((const float*)in)[idx] : bf2f(((const __hip_bfloat16*)in)[idx]);
        t[c][p] = v;
    }
    __syncthreads();
#pragma unroll
    for (int i = 0; i < 8; ++i) {
        int e = threadIdx.x + i * 256;
        int p = e >> 5, c = e & 31;
        out[((size_t)b * HW + pbase + p) * CT + coff + cbase + c] = f2bf(t[c][p]);
    }
}

// ---------------------------------------------------------------------------
// Pack conv weights [Cout][CIN][3][3] (flag dtype) into MFMA B-fragment
// order, layout [kc][tap][nc][lane][8]: k = kc*32 + (lane>>4)*8 + j,
// n = nc*16 + (lane&15). n >= Creal -> 0.
// ---------------------------------------------------------------------------
__global__ __launch_bounds__(256)
void pack_w(const void* __restrict__ w, unsigned short* __restrict__ pkw,
            int Creal, int CIN, int NC, int KC, const int* __restrict__ flag) {
    int gid = blockIdx.x * 256 + threadIdx.x;
    int total = 9 * KC * NC * 64;
    if (gid >= total) return;
    const int f32 = flag[0];
    int lane = gid & 63; int q = gid >> 6;
    int nc = q % NC; q /= NC; int tap = q % 9; int kc = q / 9;
    int lm = lane & 15, lk = lane >> 4;
    int n = nc * 16 + lm;
    int kh = tap / 3, kw = tap - kh * 3;
    ushort8 v;
#pragma unroll
    for (int j = 0; j < 8; ++j) {
        int k = kc * 32 + lk * 8 + j;
        float f = 0.f;
        if (n < Creal) {
            size_t si = (((size_t)n * CIN + k) * 3 + kh) * 3 + kw;
            f = f32 ? ((const float*)w)[si] : bf2f(((const __hip_bfloat16*)w)[si]);
        }
        v[j] = f2bf(f);
    }
    *(ushort8*)(pkw + (size_t)gid * 8) = v;
}

// ---------------------------------------------------------------------------
// Spatial-tile MFMA conv: block = 8x32 output pixels x NT*16 channels.
// Per 32-ch k-chunk: stage input tile (halo, zero-padded) + all-9-tap weights
// into LDS once, then sweep taps from LDS. Input LDS layout [j16B][row][col]
// (minimal-phase b128 reads). Upsample folded into LDS read index; conv
// padding folded into staging zero-fill.
//   EPI: 0 = *scale[b][co]+relu   1 = +bias[co]+relu   (NHWC bf16 out)
// ---------------------------------------------------------------------------
template<int CT, int H, int W, bool UP, int NT, int NCT, int EPI, int CTO>
__global__ __launch_bounds__(256, 3)
void conv_tile(const unsigned short* __restrict__ in,   // NHWC [B,SH,SW,CT]
               const unsigned short* __restrict__ pkw,  // [kc][tap][nc][64][8]
               const float* __restrict__ sb,
               unsigned short* __restrict__ outp) {
    constexpr int KC = CT / 32;
    constexpr int SH = UP ? H / 2 : H;
    constexpr int SW = UP ? W / 2 : W;
    constexpr int NROW = UP ? 6 : 10;
    constexpr int NCOL = UP ? 18 : 34;
    constexpr int NPIX = NROW * NCOL;
    constexpr int NUNIT = 4 * NPIX;          // 16B units per k-chunk tile
    constexpr int TILES_X = W / 32;
    constexpr int DCOL = UP ? 8 : 16;        // LDS col delta for second m-half

    __shared__ __align__(16) unsigned short inA[NUNIT * 8];       // [j][sr][sc]
    __shared__ __align__(16) unsigned short wbuf[9 * NT * 512];   // [tap][nc][lane][8]

    const int tid = threadIdx.x;
    const int wave = tid >> 6, lane = tid & 63;
    const int lm = lane & 15, lk = lane >> 4;
    const int x0 = (blockIdx.x % TILES_X) * 32;
    const int y0 = (blockIdx.x / TILES_X) * 8;
    const int nco0 = blockIdx.y * NT;        // n-sub base
    const int b = blockIdx.z;

    const int sy0 = UP ? ((y0 - 1) >> 1) : (y0 - 1);
    const int sx0 = UP ? ((x0 - 1) >> 1) : (x0 - 1);

    const unsigned short* gin = in + (size_t)b * SH * SW * CT;

    f32x4 acc[4][NT];
#pragma unroll
    for (int t = 0; t < 4; ++t)
#pragma unroll
        for (int u = 0; u < NT; ++u)
            acc[t][u] = f32x4{0.f, 0.f, 0.f, 0.f};

    for (int kc = 0; kc < KC; ++kc) {
        __syncthreads();
        // ---- stage input tile (zero halo) ----
        for (int u0 = tid; u0 < NUNIT; u0 += 256) {
            int pix = u0 >> 2, j = u0 & 3;
            int sr = pix / NCOL, sc = pix - sr * NCOL;
            int gy = sy0 + sr, gx = sx0 + sc;
            uint4 v = uint4{0u, 0u, 0u, 0u};
            if (gy >= 0 && gy < SH && gx >= 0 && gx < SW)
                v = *(const uint4*)((const char*)gin +
                      ((size_t)(gy * SW + gx) * CT + kc * 32) * 2 + j * 16);
            *(uint4*)((char*)inA + (((j * NROW + sr) * NCOL + sc) << 4)) = v;
        }
        // ---- stage all-9-tap weights for this k-chunk ----
        {
            const char* wsrc = (const char*)pkw;
            for (int u0 = tid; u0 < 9 * NT * 64; u0 += 256) {
                int tap = u0 / (NT * 64);
                int rem = u0 - tap * (NT * 64);
                size_t soff = ((size_t)(kc * 9 + tap) * NCT + nco0) * 1024 + (size_t)rem * 16;
                uint4 v = *(const uint4*)(wsrc + soff);
                *(uint4*)((char*)wbuf + (size_t)u0 * 16) = v;
            }
        }
        __syncthreads();
        // ---- 9-tap sweep from LDS ----
#pragma unroll
        for (int tap = 0; tap < 9; ++tap) {
            const int dy = tap / 3 - 1, dx = tap - (tap / 3) * 3 - 1;
            int srow0, srow1, scol0;
            if (UP) {
                srow0 = ((y0 + 2 * wave + dy) >> 1) - sy0;
                srow1 = ((y0 + 2 * wave + 1 + dy) >> 1) - sy0;
                scol0 = ((x0 + lm + dx) >> 1) - sx0;
            } else {
                srow0 = 2 * wave + dy + 1;
                srow1 = srow0 + 1;
                scol0 = lm + dx + 1;
            }
            const int base0 = (lk * NROW + srow0) * NCOL + scol0;
            const int base1 = (lk * NROW + srow1) * NCOL + scol0;
            short8 afr[4];
            afr[0] = *(const short8*)((const char*)inA + (base0 << 4));
            afr[1] = *(const short8*)((const char*)inA + ((base0 + DCOL) << 4));
            afr[2] = *(const short8*)((const char*)inA + (base1 << 4));
            afr[3] = *(const short8*)((const char*)inA + ((base1 + DCOL) << 4));
#pragma unroll
            for (int u = 0; u < NT; ++u) {
                short8 bfr = *(const short8*)((const char*)wbuf +
                                (((tap * NT + u) * 64 + lane) << 4));
#pragma unroll
                for (int t = 0; t < 4; ++t)
                    acc[t][u] = __builtin_amdgcn_mfma_f32_16x16x32_bf16(
                        afr[t], bfr, acc[t][u], 0, 0, 0);
            }
        }
    }

    // ---- epilogue: D col(lane&15)=N, row(lane>>4)*4+r = M ----
#pragma unroll
    for (int u = 0; u < NT; ++u) {
        const int co = (nco0 + u) * 16 + lm;
        const float s = (EPI == 0) ? sb[b * (NCT * 16) + co] : sb[co];
#pragma unroll
        for (int t = 0; t < 4; ++t) {
            const int row = y0 + 2 * wave + (t >> 1);
            const int colb = x0 + (t & 1) * 16 + lk * 4;
            const size_t pbase = ((size_t)b * H + row) * W + colb;
#pragma unroll
            for (int rr = 0; rr < 4; ++rr) {
                float v = acc[t][u][rr];
                v = (EPI == 0) ? v * s : v + s;
                v = fmaxf(v, 0.f);
                outp[(pbase + rr) * CTO + co] = f2bf(v);
            }
        }
    }
}

// ---------------------------------------------------------------------------
// Round-3 implicit-GEMM conv (kept for L4: Cout=3, NCHW external store).
// Weight staging updated to the [kc][tap][nc] pack layout.
// ---------------------------------------------------------------------------
template<int CT, int H, int W, bool UP, int NT, int NC, int KCS, int EPI, int CTO>
__global__ __launch_bounds__(256)
void conv_mfma(const unsigned short* __restrict__ in,
               const unsigned short* __restrict__ pkw,
               const float* __restrict__ sb,
               void* __restrict__ outv,
               const int* __restrict__ flagp) {
    constexpr int KC = CT / 32;
    constexpr int HW = H * W;
    constexpr int LHW = cilog2(HW);
    constexpr int LW = cilog2(W);
    constexpr int SW = UP ? W / 2 : W;
    constexpr int SH = UP ? H / 2 : H;
    constexpr int STAGES = KC / KCS;
    __shared__ __align__(16) unsigned short lds[KCS * NT * 512];

    const int tid = threadIdx.x;
    const int wave = tid >> 6, lane = tid & 63;
    const int lm = lane & 15, lk = lane >> 4;
    const int blkm = blockIdx.x * 256;
    const int nco0 = blockIdx.y * NT;

    int pb[4], py[4], px[4];
#pragma unroll
    for (int t = 0; t < 4; ++t) {
        int P = blkm + wave * 64 + t * 16 + lm;
        pb[t] = P >> LHW;
        int rem = P & (HW - 1);
        py[t] = rem >> LW;
        px[t] = rem & (W - 1);
    }

    f32x4 acc[4][NT];
#pragma unroll
    for (int t = 0; t < 4; ++t)
#pragma unroll
        for (int u = 0; u < NT; ++u)
            acc[t][u] = f32x4{0.f, 0.f, 0.f, 0.f};

    for (int tap = 0; tap < 9; ++tap) {
        const int dy = tap / 3 - 1, dx = tap - (tap / 3) * 3 - 1;
        int ab[4]; bool av[4];
#pragma unroll
        for (int t = 0; t < 4; ++t) {
            int ty = py[t] + dy, tx = px[t] + dx;
            av[t] = (ty >= 0) && (ty < H) && (tx >= 0) && (tx < W);
            int iy = UP ? (ty >> 1) : ty;
            int ix = UP ? (tx >> 1) : tx;
            iy = av[t] ? iy : 0; ix = av[t] ? ix : 0;
            ab[t] = (((pb[t] * SH + iy) * SW + ix) * CT + lk * 8) * 2;
        }
        for (int st = 0; st < STAGES; ++st) {
            const int kc0 = st * KCS;
            __syncthreads();
            {
                constexpr int T16 = KCS * NT * 64;
                const char* pwb = (const char*)pkw;
                for (int f = tid; f < T16; f += 256) {
                    int fb = f * 16;
                    int kcl = fb / (NT * 1024);
                    int rem2 = fb - kcl * (NT * 1024);
                    int soff = (((kc0 + kcl) * 9 + tap) * NC + nco0) * 1024 + rem2;
                    uint4 v = *(const uint4*)(pwb + soff);
                    *(uint4*)((char*)lds + fb) = v;
                }
            }
            __syncthreads();
#pragma unroll 4
            for (int kcl = 0; kcl < KCS; ++kcl) {
                short8 a[4];
#pragma unroll
                for (int t = 0; t < 4; ++t) {
                    uint4 raw = *(const uint4*)((const char*)in + (ab[t] + (kc0 + kcl) * 64));
                    uint4 z = uint4{0u, 0u, 0u, 0u};
                    uint4 sel = av[t] ? raw : z;
                    a[t] = *(short8*)&sel;
                }
#pragma unroll
                for (int u = 0; u < NT; ++u) {
                    short8 bfr = *(short8*)((char*)lds + (kcl * NT + u) * 1024 + lane * 16);
#pragma unroll
                    for (int t = 0; t < 4; ++t)
                        acc[t][u] = __builtin_amdgcn_mfma_f32_16x16x32_bf16(
                            a[t], bfr, acc[t][u], 0, 0, 0);
                }
            }
        }
    }

    const int f32o = flagp[0];
    const int co = lm;                    // NT == 1, Cout=3
    if (co < 3) {
        const float bias = sb[co];
#pragma unroll
        for (int t = 0; t < 4; ++t) {
            const int Pb = blkm + wave * 64 + t * 16 + lk * 4;
#pragma unroll
            for (int r = 0; r < 4; ++r) {
                const int P = Pb + r;
                const int bb = P >> LHW;
                const int rem = P & (HW - 1);
                const float v = acc[t][0][r] + bias;
                const int oi = (bb * 3 + co) * HW + rem;
                if (f32o) ((float*)outv)[oi] = v;
                else ((unsigned short*)outv)[oi] = f2bf(v);
            }
        }
    }
}

// ===========================================================================
// FALLBACK direct conv (round-2 proven) — used only if ws too small
// ===========================================================================
template<int CIN, int CSPLIT, int H, int W, bool UP, int CO_TILE, int EPI,
         bool D0, bool D1, bool DOUT>
__global__ __launch_bounds__(256)
void conv3x3(const void* __restrict__ p0, const void* __restrict__ p1,
             const float* __restrict__ wf, const float* __restrict__ sb,
             void* __restrict__ outv, int Cout, const int* __restrict__ flagp) {
    __shared__ float tile[18 * 20];
    constexpr int SH = UP ? H / 2 : H;
    constexpr int SW = UP ? W / 2 : W;
    constexpr int C0 = CSPLIT;
    constexpr int TX = W / 16;

    const int f32 = __builtin_amdgcn_readfirstlane(flagp[0]);
    const int esz0 = (D0 && f32) ? 4 : 2;
    const int esz1 = (D1 && f32) ? 4 : 2;

    const int tid = threadIdx.x;
    const int tx = tid & 15, ty = tid >> 4;
    const int x0 = (blockIdx.x % TX) * 16;
    const int y0 = (blockIdx.x / TX) * 16;
    const int co0 = blockIdx.y * CO_TILE;
    const int b = blockIdx.z;

    const char* bb0 = (const char*)p0 + (size_t)b * C0 * SH * SW * esz0;
    const char* bb1 = (const char*)p1 + (size_t)b * (CIN - C0) * SH * SW * esz1;

    int ly1 = tid / 18, lx1 = tid - ly1 * 18;
    int yy1 = y0 - 1 + ly1, xx1 = x0 - 1 + lx1;
    bool in1 = (yy1 >= 0) && (yy1 < H) && (xx1 >= 0) && (xx1 < W);
    int sof1 = in1 ? ((UP ? (yy1 >> 1) : yy1) * SW + (UP ? (xx1 >> 1) : xx1)) : 0;
    float* tp1 = tile + ly1 * 20 + lx1;

    int t2 = tid + 256;
    bool has2 = (t2 < 324);
    int t2c = has2 ? t2 : 0;
    int ly2 = t2c / 18, lx2 = t2c - ly2 * 18;
    int yy2 = y0 - 1 + ly2, xx2 = x0 - 1 + lx2;
    bool in2 = has2 && (yy2 >= 0) && (yy2 < H) && (xx2 >= 0) && (xx2 < W);
    int sof2 = in2 ? ((UP ? (yy2 >> 1) : yy2) * SW + (UP ? (xx2 >> 1) : xx2)) : 0;
    float* tp2 = tile + ly2 * 20 + lx2;

    float acc[CO_TILE];
#pragma unroll
    for (int j = 0; j < CO_TILE; ++j) acc[j] = 0.f;
    const float* wbase = wf + (size_t)co0 * CIN * 9;

    for (int ci = 0; ci < CIN; ++ci) {
        bool isP0 = (ci < C0);
        const char* src = isP0 ? bb0 + (size_t)ci * SH * SW * esz0
                               : bb1 + (size_t)(ci - C0) * SH * SW * esz1;
        bool sf = isP0 ? (D0 && f32) : (D1 && f32);
        __syncthreads();
        float v1 = 0.f, v2 = 0.f;
        if (sf) {
            if (in1) v1 = ((const float*)src)[sof1];
            if (in2) v2 = ((const float*)src)[sof2];
        } else {
            if (in1) v1 = bf2f(((const __hip_bfloat16*)src)[sof1]);
            if (in2) v2 = bf2f(((const __hip_bfloat16*)src)[sof2]);
        }
        tp1[0] = v1;
        if (has2) tp2[0] = v2;
        __syncthreads();

        float v[9];
#pragma unroll
        for (int r = 0; r < 3; ++r)
#pragma unroll
            for (int c = 0; c < 3; ++c)
                v[r * 3 + c] = tile[(ty + r) * 20 + tx + c];

        const float* wp = wbase + ci * 9;
#pragma unroll
        for (int j = 0; j < CO_TILE; ++j) {
            const float* w9 = wp + (size_t)j * CIN * 9;
#pragma unroll
            for (int k = 0; k < 9; ++k)
                acc[j] = fmaf(v[k], w9[k], acc[j]);
        }
    }

    const int oy = y0 + ty, ox = x0 + tx;
#pragma unroll
    for (int j = 0; j < CO_TILE; ++j) {
        const int co = co0 + j;
        float val = acc[j];
        if (EPI == 0)      val = fmaxf(val * sb[b * Cout + co], 0.f);
        else if (EPI == 1) val = fmaxf(val + sb[co], 0.f);
        else               val = val + sb[co];
        size_t oidx = (((size_t)b * Cout + co) * H + oy) * W + ox;
        if (DOUT && f32) ((float*)outv)[oidx] = val;
        else ((__hip_bfloat16*)outv)[oidx] = __float2bfloat16(val);
    }
}

// ---------------------------------------------------------------------------
// Launch
// ---------------------------------------------------------------------------
extern "C" void kernel_launch(void* const* d_in, const int* in_sizes, int n_in,
                              void* d_out, int out_size, void* d_ws, size_t ws_size,
                              hipStream_t stream) {
    const void* x     = d_in[0];   const void* enc1  = d_in[1];
    const void* enc2  = d_in[2];   const void* enc3  = d_in[3];
    const void* style = d_in[4];
    const void* w1    = d_in[5];   const void* fcw1  = d_in[6];  const void* fcb1 = d_in[7];
    const void* w2    = d_in[8];   const void* fcw2  = d_in[9];  const void* fcb2 = d_in[10];
    const void* fw1   = d_in[11];  const void* fb1   = d_in[12];
    const void* fw2   = d_in[13];  const void* fb2   = d_in[14];
    char* ws = (char*)d_ws;
    auto gb = [](int n) { return (n + 255) / 256; };

    constexpr size_t REQ = 272629760ULL;  // 4MB + 67MB + 67MB + 134MB

    if (ws_size >= REQ) {
        unsigned short* pkw1 = (unsigned short*)(ws + 0);
        unsigned short* pkw2 = (unsigned short*)(ws + 1179648);
        unsigned short* pkw3 = (unsigned short*)(ws + 1474560);
        unsigned short* pkw4 = (unsigned short*)(ws + 1622016);
        float* s1    = (float*)(ws + 1640448);
        float* s2    = (float*)(ws + 1644544);
        float* fb1f  = (float*)(ws + 1646592);
        float* fb2f  = (float*)(ws + 1646848);
        int*   flag  = (int*)(ws + 1646912);
        unsigned short* buf0 = (unsigned short*)(ws + (4u << 20));              // [B,64,64,512]
        unsigned short* h3   = (unsigned short*)(ws + (4u << 20));              // [B,256,256,64]
        unsigned short* buf1 = (unsigned short*)(ws + (4u << 20) + 67108864u);  // [B,128,128,256]
        unsigned short* buf2 = (unsigned short*)(ws + (4u << 20) + 134217728u); // [B,256,256,128]

        hipLaunchKernelGGL(detect_dtype, dim3(1), dim3(256), 0, stream,
                           (const unsigned short*)style, flag);

        hipLaunchKernelGGL(nchw_to_nhwc, dim3(64, 8, 8),   dim3(256), 0, stream, x,    buf0, 256, 4096,  512, 0,   flag);
        hipLaunchKernelGGL(nchw_to_nhwc, dim3(64, 8, 8),   dim3(256), 0, stream, enc3, buf0, 256, 4096,  512, 256, flag);
        hipLaunchKernelGGL(nchw_to_nhwc, dim3(256, 4, 8),  dim3(256), 0, stream, enc2, buf1, 128, 16384, 256, 128, flag);
        hipLaunchKernelGGL(nchw_to_nhwc, dim3(1024, 2, 8), dim3(256), 0, stream, enc1, buf2, 64,  65536, 128, 64,  flag);

        hipLaunchKernelGGL(pack_w, dim3(gb(73728)), dim3(256), 0, stream, w1,  pkw1, 128, 512, 8, 16, flag);
        hipLaunchKernelGGL(pack_w, dim3(gb(18432)), dim3(256), 0, stream, w2,  pkw2, 64,  256, 4, 8,  flag);
        hipLaunchKernelGGL(pack_w, dim3(gb(9216)),  dim3(256), 0, stream, fw1, pkw3, 64,  128, 4, 4,  flag);
        hipLaunchKernelGGL(pack_w, dim3(gb(1152)),  dim3(256), 0, stream, fw2, pkw4, 3,   64,  1, 2,  flag);

        hipLaunchKernelGGL(style_mod, dim3(4), dim3(256), 0, stream, style, fcw1, fcb1, s1, 8, 128, 256, flag);
        hipLaunchKernelGGL(style_mod, dim3(2), dim3(256), 0, stream, style, fcw2, fcb2, s2, 8, 64, 256, flag);
        hipLaunchKernelGGL(cvt_pad_f32, dim3(1), dim3(256), 0, stream, fb1, fb1f, 64, 64, flag);
        hipLaunchKernelGGL(cvt_pad_f32, dim3(1), dim3(256), 0, stream, fb2, fb2f, 3, 16, flag);

        // L1: buf0 [B,64,64,512] -up2-> buf1 ch0-127; N split in 2
        hipLaunchKernelGGL((conv_tile<512, 128, 128, true, 4, 8, 0, 256>),
                           dim3(64, 2, 8), dim3(256), 0, stream, buf0, pkw1, s1, buf1);
        // L2: buf1 [B,128,128,256] -up2-> buf2 ch0-63
        hipLaunchKernelGGL((conv_tile<256, 256, 256, true, 4, 4, 0, 128>),
                           dim3(256, 1, 8), dim3(256), 0, stream, buf1, pkw2, s2, buf2);
        // L3: buf2 [B,256,256,128] -> h3 [B,256,256,64]
        hipLaunchKernelGGL((conv_tile<128, 256, 256, false, 4, 4, 1, 64>),
                           dim3(256, 1, 8), dim3(256), 0, stream, buf2, pkw3, fb1f, h3);
        // L4: h3 -> d_out NCHW [B,3,256,256]
        hipLaunchKernelGGL((conv_mfma<64, 256, 256, false, 1, 1, 2, 2, 0>),
                           dim3(2048, 1), dim3(256), 0, stream, h3, pkw4, fb2f, d_out, flag);
        return;
    }

    // ---- fallback path ----
    float* w1f  = (float*)(ws + 0);
    float* w2f  = (float*)(ws + 2359296);
    float* fw1f = (float*)(ws + 2949120);
    float* fw2f = (float*)(ws + 3244032);
    float* s1   = (float*)(ws + 3250944);
    float* s2   = (float*)(ws + 3255040);
    float* fb1f = (float*)(ws + 3257088);
    float* fb2f = (float*)(ws + 3257344);
    int*   flag = (int*)(ws + 3257360);
    __hip_bfloat16* h1 = (__hip_bfloat16*)(ws + (size_t)(4u << 20));
    __hip_bfloat16* h3 = (__hip_bfloat16*)(ws + (size_t)(4u << 20));
    __hip_bfloat16* h2 = (__hip_bfloat16*)(ws + (size_t)(4u << 20) + 67108864u);

    hipLaunchKernelGGL(detect_dtype, dim3(1), dim3(256), 0, stream,
                       (const unsigned short*)style, flag);
    hipLaunchKernelGGL(cvt_pad_f32, dim3(gb(589824)), dim3(256), 0, stream, w1, w1f, 589824, 589824, flag);
    hipLaunchKernelGGL(cvt_pad_f32, dim3(gb(147456)), dim3(256), 0, stream, w2, w2f, 147456, 147456, flag);
    hipLaunchKernelGGL(cvt_pad_f32, dim3(gb(73728)),  dim3(256), 0, stream, fw1, fw1f, 73728, 73728, flag);
    hipLaunchKernelGGL(cvt_pad_f32, dim3(gb(1728)),   dim3(256), 0, stream, fw2, fw2f, 1728, 1728, flag);
    hipLaunchKernelGGL(cvt_pad_f32, dim3(1), dim3(256), 0, stream, fb1, fb1f, 64, 64, flag);
    hipLaunchKernelGGL(cvt_pad_f32, dim3(1), dim3(256), 0, stream, fb2, fb2f, 3, 3, flag);
    hipLaunchKernelGGL(style_mod, dim3(4), dim3(256), 0, stream, style, fcw1, fcb1, s1, 8, 128, 256, flag);
    hipLaunchKernelGGL(style_mod, dim3(2), dim3(256), 0, stream, style, fcw2, fcb2, s2, 8, 64, 256, flag);

    hipLaunchKernelGGL((conv3x3<512, 256, 128, 128, true, 8, 0, true, true, false>),
                       dim3(64, 16, 8), dim3(256), 0, stream, x, enc3, w1f, s1, h1, 128, flag);
    hipLaunchKernelGGL((conv3x3<256, 128, 256, 256, true, 8, 0, false, true, false>),
                       dim3(256, 8, 8), dim3(256), 0, stream, h1, enc2, w2f, s2, h2, 64, flag);
    hipLaunchKernelGGL((conv3x3<128, 64, 256, 256, false, 8, 1, false, true, false>),
                       dim3(256, 8, 8), dim3(256), 0, stream, h2, enc1, fw1f, fb1f, h3, 64, flag);
    hipLaunchKernelGGL((conv3x3<64, 64, 256, 256, false, 3, 2, false, false, true>),
                       dim3(256, 1, 8), dim3(256), 0, stream, h3, h3, fw2f, fb2f, d_out, 3, flag);
}

// Round 5
// 807.181 us; speedup vs baseline: 9.9611x; 1.1299x over previous
//
#include <hip/hip_runtime.h>
#include <hip/hip_bf16.h>
#include <cstdint>
#include <cstddef>

typedef short short8 __attribute__((ext_vector_type(8)));
typedef unsigned short ushort8 __attribute__((ext_vector_type(8)));
typedef float f32x4 __attribute__((ext_vector_type(4)));

#define DI __device__ __forceinline__

DI float bf2f(__hip_bfloat16 h) { return __bfloat162float(h); }
DI unsigned short f2bf(float f) {
    __hip_bfloat16 h = __float2bfloat16(f);
    return *(unsigned short*)&h;
}

constexpr int cilog2(int v) { int r = 0; while (v > 1) { v >>= 1; ++r; } return r; }

// ---------------------------------------------------------------------------
// dtype sniffer (1 = fp32 external tensors, 0 = bf16)
// ---------------------------------------------------------------------------
__global__ void detect_dtype(const unsigned short* __restrict__ raw,
                             int* __restrict__ flag) {
    __shared__ int cnt;
    if (threadIdx.x == 0) cnt = 0;
    __syncthreads();
    int local = 0;
    for (int i = threadIdx.x; i < 1024; i += 256) {
        unsigned short u = raw[2 * i];
        int e = (u >> 7) & 0xFF;
        if (e >= 110 && e <= 132) local++;
    }
    atomicAdd(&cnt, local);
    __syncthreads();
    if (threadIdx.x == 0) *flag = (cnt < 512) ? 1 : 0;
}

// ---------------------------------------------------------------------------
// dual-dtype -> fp32, zero-padded to npad
// ---------------------------------------------------------------------------
__global__ void cvt_pad_f32(const void* __restrict__ in, float* __restrict__ out,
                            int n, int npad, const int* __restrict__ flag) {
    int i = blockIdx.x * blockDim.x + threadIdx.x;
    if (i >= npad) return;
    float v = 0.f;
    if (i < n) v = (*flag) ? ((const float*)in)[i] : bf2f(((const __hip_bfloat16*)in)[i]);
    out[i] = v;
}

// ---------------------------------------------------------------------------
// style modulation scales
// ---------------------------------------------------------------------------
__global__ void style_mod(const void* __restrict__ style, const void* __restrict__ fcw,
                          const void* __restrict__ fcb, float* __restrict__ out,
                          int B, int O, int S, const int* __restrict__ flag) {
    int i = blockIdx.x * blockDim.x + threadIdx.x;
    if (i >= B * O) return;
    int b = i / O, o = i - b * O;
    float acc = 0.f;
    if (*flag) {
        const float* sp = (const float*)style + (size_t)b * S;
        const float* wp = (const float*)fcw + (size_t)o * S;
        for (int k = 0; k < S; ++k) acc = fmaf(sp[k], wp[k], acc);
        acc += ((const float*)fcb)[o];
    } else {
        const __hip_bfloat16* sp = (const __hip_bfloat16*)style + (size_t)b * S;
        const __hip_bfloat16* wp = (const __hip_bfloat16*)fcw + (size_t)o * S;
        for (int k = 0; k < S; ++k) acc = fmaf(bf2f(sp[k]), bf2f(wp[k]), acc);
        acc += bf2f(((const __hip_bfloat16*)fcb)[o]);
    }
    out[i] = acc;
}

// ---------------------------------------------------------------------------
// NCHW (flag dtype) -> NHWC bf16 into channel slot [coff, coff+C)
// ---------------------------------------------------------------------------
__global__ __launch_bounds__(256)
void nchw_to_nhwc(const void* __restrict__ in, unsigned short* __restrict__ out,
                  int C, int HW, int CT, int coff, const int* __restrict__ flag) {
    __shared__ float t[32][65];
    const int f32 = flag[0];
    const int pbase = blockIdx.x * 64;
    const int cbase = blockIdx.y * 32;
    const int b = blockIdx.z;
    const size_t ibase = ((size_t)b * C + cbase) * HW + pbase;
#pragma unroll
    for (int i = 0; i < 8; ++i) {
        int e = threadIdx.x + i * 256;
        int c = e >> 6, p = e & 63;
        size_t idx = ibase + (size_t)c * HW + p;
        float v = f32 ? ((const float*)in)[idx] : bf2f(((const __hip_bfloat16*)in)[idx]);
        t[c][p] = v;
    }
    __syncthreads();
#pragma unroll
    for (int i = 0; i < 8; ++i) {
        int e = threadIdx.x + i * 256;
        int p = e >> 5, c = e & 31;
        out[((size_t)b * HW + pbase + p) * CT + coff + cbase + c] = f2bf(t[c][p]);
    }
}

// ---------------------------------------------------------------------------
// Pack conv weights [Cout][CIN][3][3] (flag dtype) into MFMA B-fragment
// order, layout [kc][tap][nc][lane][8]: k = kc*32 + (lane>>4)*8 + j,
// n = nc*16 + (lane&15). n >= Creal -> 0.
// ---------------------------------------------------------------------------
__global__ __launch_bounds__(256)
void pack_w(const void* __restrict__ w, unsigned short* __restrict__ pkw,
            int Creal, int CIN, int NC, int KC, const int* __restrict__ flag) {
    int gid = blockIdx.x * 256 + threadIdx.x;
    int total = 9 * KC * NC * 64;
    if (gid >= total) return;
    const int f32 = flag[0];
    int lane = gid & 63; int q = gid >> 6;
    int nc = q % NC; q /= NC; int tap = q % 9; int kc = q / 9;
    int lm = lane & 15, lk = lane >> 4;
    int n = nc * 16 + lm;
    int kh = tap / 3, kw = tap - kh * 3;
    ushort8 v;
#pragma unroll
    for (int j = 0; j < 8; ++j) {
        int k = kc * 32 + lk * 8 + j;
        float f = 0.f;
        if (n < Creal) {
            size_t si = (((size_t)n * CIN + k) * 3 + kh) * 3 + kw;
            f = f32 ? ((const float*)w)[si] : bf2f(((const __hip_bfloat16*)w)[si]);
        }
        v[j] = f2bf(f);
    }
    *(ushort8*)(pkw + (size_t)gid * 8) = v;
}

// ---------------------------------------------------------------------------
// UP-specialized spatial-tile MFMA conv (fused nearest-2x upsample).
// Block = 16x32 output pixels, 4 waves, each wave 4 rows x 32 cols = 128 px
// as 8 m-tiles: (ro in 0..3, parity p in 0..1), m-index lm -> col x0+2*lm+p.
// Upsample duplication makes tap->source mapping lane-uniform:
//   A-frag = F[fr][wn], fr=(ro+dy+2)>>1 (4 rows), wn=(p+dx+2)>>1 (3 windows)
// -> only 12 LDS A-reads serve all 288 MFMA per k-chunk per wave.
// EPI0: *scale[b][co]+relu, NHWC bf16 out.
// ---------------------------------------------------------------------------
template<int CT, int H, int W, int NT, int NCT, int CTO>
__global__ __launch_bounds__(256, 2)
void conv_tile_up(const unsigned short* __restrict__ in,   // NHWC [B,H/2,W/2,CT]
                  const unsigned short* __restrict__ pkw,  // [kc][tap][nc][64][8]
                  const float* __restrict__ sb,
                  unsigned short* __restrict__ outp) {
    constexpr int KC = CT / 32;
    constexpr int SH = H / 2, SW = W / 2;
    constexpr int NROW = 10, NCOL = 18;
    constexpr int NPIX = NROW * NCOL;        // 180
    constexpr int NUNIT = 4 * NPIX;          // 720 x16B = 11.5 KB
    constexpr int TILES_X = W / 32;

    __shared__ __align__(16) unsigned short inA[NUNIT * 8];       // [j][sr][sc]
    __shared__ __align__(16) unsigned short wbuf[9 * NT * 512];   // [tap][nc][lane][8]

    const int tid = threadIdx.x;
    const int wave = tid >> 6, lane = tid & 63;
    const int lm = lane & 15, lk = lane >> 4;
    const int x0 = (blockIdx.x % TILES_X) * 32;
    const int y0 = (blockIdx.x / TILES_X) * 16;
    const int nco0 = blockIdx.y * NT;
    const int b = blockIdx.z;

    const int sy0 = (y0 - 1) >> 1;           // = y0/2 - 1
    const int sx0 = (x0 - 1) >> 1;           // = x0/2 - 1

    const unsigned short* gin = in + (size_t)b * SH * SW * CT;

    f32x4 acc[8][NT];
#pragma unroll
    for (int t = 0; t < 8; ++t)
#pragma unroll
        for (int u = 0; u < NT; ++u)
            acc[t][u] = f32x4{0.f, 0.f, 0.f, 0.f};

    for (int kc = 0; kc < KC; ++kc) {
        __syncthreads();
        // stage input tile (zero halo)
        for (int u0 = tid; u0 < NUNIT; u0 += 256) {
            int pix = u0 >> 2, j = u0 & 3;
            int sr = pix / NCOL, sc = pix - sr * NCOL;
            int gy = sy0 + sr, gx = sx0 + sc;
            uint4 v = uint4{0u, 0u, 0u, 0u};
            if (gy >= 0 && gy < SH && gx >= 0 && gx < SW)
                v = *(const uint4*)((const char*)gin +
                      ((size_t)(gy * SW + gx) * CT + kc * 32) * 2 + j * 16);
            *(uint4*)((char*)inA + (((j * NROW + sr) * NCOL + sc) << 4)) = v;
        }
        // stage all-9-tap weights for this k-chunk
        for (int u0 = tid; u0 < 9 * NT * 64; u0 += 256) {
            int tap = u0 / (NT * 64);
            int rem = u0 - tap * (NT * 64);
            size_t soff = ((size_t)(kc * 9 + tap) * NCT + nco0) * 1024 + (size_t)rem * 16;
            uint4 v = *(const uint4*)((const char*)pkw + soff);
            *(uint4*)((char*)wbuf + (size_t)u0 * 16) = v;
        }
        __syncthreads();

        // 12 A-fragments cover all taps/m-tiles for this chunk
        short8 F[4][3];
#pragma unroll
        for (int fr = 0; fr < 4; ++fr)
#pragma unroll
            for (int wn = 0; wn < 3; ++wn)
                F[fr][wn] = *(const short8*)((const char*)inA +
                    ((((lk * NROW + 2 * wave + fr) * NCOL) + lm + wn) << 4));

#pragma unroll
        for (int tap = 0; tap < 9; ++tap) {
            const int dy = tap / 3 - 1, dx = tap - (tap / 3) * 3 - 1;
#pragma unroll
            for (int u = 0; u < NT; ++u) {
                short8 bfr = *(const short8*)((const char*)wbuf +
                                (((tap * NT + u) * 64 + lane) << 4));
#pragma unroll
                for (int ro = 0; ro < 4; ++ro)
#pragma unroll
                    for (int p = 0; p < 2; ++p)
                        acc[ro * 2 + p][u] = __builtin_amdgcn_mfma_f32_16x16x32_bf16(
                            F[(ro + dy + 2) >> 1][(p + dx + 2) >> 1], bfr,
                            acc[ro * 2 + p][u], 0, 0, 0);
            }
        }
    }

    // epilogue: D col(lane&15)=N, m=(lane>>4)*4+rr -> out col x0+2*m+p
#pragma unroll
    for (int u = 0; u < NT; ++u) {
        const int co = (nco0 + u) * 16 + lm;
        const float s = sb[b * (NCT * 16) + co];
#pragma unroll
        for (int ro = 0; ro < 4; ++ro) {
            const int row = y0 + 4 * wave + ro;
#pragma unroll
            for (int p = 0; p < 2; ++p) {
#pragma unroll
                for (int rr = 0; rr < 4; ++rr) {
                    const int col = x0 + 2 * (lk * 4 + rr) + p;
                    float v = fmaxf(acc[ro * 2 + p][u][rr] * s, 0.f);
                    outp[((size_t)(b * H + row) * W + col) * CTO + co] = f2bf(v);
                }
            }
        }
    }
}

// ---------------------------------------------------------------------------
// Non-UP spatial-tile MFMA conv (round-4 proven): block = 8x32 px x NT*16 ch.
// EPI: 1 = +bias[co]+relu (NHWC bf16)   2 = +bias[co], NCHW external store
// ---------------------------------------------------------------------------
template<int CT, int H, int W, int NT, int NCT, int EPI, int CTO>
__global__ __launch_bounds__(256, 3)
void conv_tile(const unsigned short* __restrict__ in,   // NHWC [B,H,W,CT]
               const unsigned short* __restrict__ pkw,  // [kc][tap][nc][64][8]
               const float* __restrict__ sb,
               void* __restrict__ outv,
               const int* __restrict__ flagp) {
    constexpr int KC = CT / 32;
    constexpr int NROW = 10;
    constexpr int NCOL = 34;
    constexpr int NPIX = NROW * NCOL;
    constexpr int NUNIT = 4 * NPIX;
    constexpr int TILES_X = W / 32;

    __shared__ __align__(16) unsigned short inA[NUNIT * 8];
    __shared__ __align__(16) unsigned short wbuf[9 * NT * 512];

    const int tid = threadIdx.x;
    const int wave = tid >> 6, lane = tid & 63;
    const int lm = lane & 15, lk = lane >> 4;
    const int x0 = (blockIdx.x % TILES_X) * 32;
    const int y0 = (blockIdx.x / TILES_X) * 8;
    const int nco0 = blockIdx.y * NT;
    const int b = blockIdx.z;

    const int sy0 = y0 - 1, sx0 = x0 - 1;
    const unsigned short* gin = in + (size_t)b * H * W * CT;

    f32x4 acc[4][NT];
#pragma unroll
    for (int t = 0; t < 4; ++t)
#pragma unroll
        for (int u = 0; u < NT; ++u)
            acc[t][u] = f32x4{0.f, 0.f, 0.f, 0.f};

    for (int kc = 0; kc < KC; ++kc) {
        __syncthreads();
        for (int u0 = tid; u0 < NUNIT; u0 += 256) {
            int pix = u0 >> 2, j = u0 & 3;
            int sr = pix / NCOL, sc = pix - sr * NCOL;
            int gy = sy0 + sr, gx = sx0 + sc;
            uint4 v = uint4{0u, 0u, 0u, 0u};
            if (gy >= 0 && gy < H && gx >= 0 && gx < W)
                v = *(const uint4*)((const char*)gin +
                      ((size_t)(gy * W + gx) * CT + kc * 32) * 2 + j * 16);
            *(uint4*)((char*)inA + (((j * NROW + sr) * NCOL + sc) << 4)) = v;
        }
        for (int u0 = tid; u0 < 9 * NT * 64; u0 += 256) {
            int tap = u0 / (NT * 64);
            int rem = u0 - tap * (NT * 64);
            size_t soff = ((size_t)(kc * 9 + tap) * NCT + nco0) * 1024 + (size_t)rem * 16;
            uint4 v = *(const uint4*)((const char*)pkw + soff);
            *(uint4*)((char*)wbuf + (size_t)u0 * 16) = v;
        }
        __syncthreads();

#pragma unroll
        for (int tap = 0; tap < 9; ++tap) {
            const int dy = tap / 3 - 1, dx = tap - (tap / 3) * 3 - 1;
            const int srow0 = 2 * wave + dy + 1;
            const int scol0 = lm + dx + 1;
            const int base0 = (lk * NROW + srow0) * NCOL + scol0;
            const int base1 = (lk * NROW + srow0 + 1) * NCOL + scol0;
            short8 afr[4];
            afr[0] = *(const short8*)((const char*)inA + (base0 << 4));
            afr[1] = *(const short8*)((const char*)inA + ((base0 + 16) << 4));
            afr[2] = *(const short8*)((const char*)inA + (base1 << 4));
            afr[3] = *(const short8*)((const char*)inA + ((base1 + 16) << 4));
#pragma unroll
            for (int u = 0; u < NT; ++u) {
                short8 bfr = *(const short8*)((const char*)wbuf +
                                (((tap * NT + u) * 64 + lane) << 4));
#pragma unroll
                for (int t = 0; t < 4; ++t)
                    acc[t][u] = __builtin_amdgcn_mfma_f32_16x16x32_bf16(
                        afr[t], bfr, acc[t][u], 0, 0, 0);
            }
        }
    }

    if constexpr (EPI == 1) {
        unsigned short* outp = (unsigned short*)outv;
#pragma unroll
        for (int u = 0; u < NT; ++u) {
            const int co = (nco0 + u) * 16 + lm;
            const float s = sb[co];
#pragma unroll
            for (int t = 0; t < 4; ++t) {
                const int row = y0 + 2 * wave + (t >> 1);
                const int colb = x0 + (t & 1) * 16 + lk * 4;
                const size_t pbase = ((size_t)(b * H + row)) * W + colb;
#pragma unroll
                for (int rr = 0; rr < 4; ++rr) {
                    float v = fmaxf(acc[t][u][rr] + s, 0.f);
                    outp[(pbase + rr) * CTO + co] = f2bf(v);
                }
            }
        }
    } else {  // EPI == 2: Cout=3, NT==1, NCHW external store
        const int f32o = flagp[0];
        const int co = lm;
        if (co < 3) {
            const float bias = sb[co];
#pragma unroll
            for (int t = 0; t < 4; ++t) {
                const int row = y0 + 2 * wave + (t >> 1);
                const int colb = x0 + (t & 1) * 16 + lk * 4;
#pragma unroll
                for (int rr = 0; rr < 4; ++rr) {
                    const float v = acc[t][0][rr] + bias;
                    const size_t oi = ((size_t)(b * 3 + co) * H + row) * W + colb + rr;
                    if (f32o) ((float*)outv)[oi] = v;
                    else ((unsigned short*)outv)[oi] = f2bf(v);
                }
            }
        }
    }
}

// ===========================================================================
// FALLBACK direct conv (round-2 proven) — used only if ws too small
// ===========================================================================
template<int CIN, int CSPLIT, int H, int W, bool UP, int CO_TILE, int EPI,
         bool D0, bool D1, bool DOUT>
__global__ __launch_bounds__(256)
void conv3x3(const void* __restrict__ p0, const void* __restrict__ p1,
             const float* __restrict__ wf, const float* __restrict__ sb,
             void* __restrict__ outv, int Cout, const int* __restrict__ flagp) {
    __shared__ float tile[18 * 20];
    constexpr int SH = UP ? H / 2 : H;
    constexpr int SW = UP ? W / 2 : W;
    constexpr int C0 = CSPLIT;
    constexpr int TX = W / 16;

    const int f32 = __builtin_amdgcn_readfirstlane(flagp[0]);
    const int esz0 = (D0 && f32) ? 4 : 2;
    const int esz1 = (D1 && f32) ? 4 : 2;

    const int tid = threadIdx.x;
    const int tx = tid & 15, ty = tid >> 4;
    const int x0 = (blockIdx.x % TX) * 16;
    const int y0 = (blockIdx.x / TX) * 16;
    const int co0 = blockIdx.y * CO_TILE;
    const int b = blockIdx.z;

    const char* bb0 = (const char*)p0 + (size_t)b * C0 * SH * SW * esz0;
    const char* bb1 = (const char*)p1 + (size_t)b * (CIN - C0) * SH * SW * esz1;

    int ly1 = tid / 18, lx1 = tid - ly1 * 18;
    int yy1 = y0 - 1 + ly1, xx1 = x0 - 1 + lx1;
    bool in1 = (yy1 >= 0) && (yy1 < H) && (xx1 >= 0) && (xx1 < W);
    int sof1 = in1 ? ((UP ? (yy1 >> 1) : yy1) * SW + (UP ? (xx1 >> 1) : xx1)) : 0;
    float* tp1 = tile + ly1 * 20 + lx1;

    int t2 = tid + 256;
    bool has2 = (t2 < 324);
    int t2c = has2 ? t2 : 0;
    int ly2 = t2c / 18, lx2 = t2c - ly2 * 18;
    int yy2 = y0 - 1 + ly2, xx2 = x0 - 1 + lx2;
    bool in2 = has2 && (yy2 >= 0) && (yy2 < H) && (xx2 >= 0) && (xx2 < W);
    int sof2 = in2 ? ((UP ? (yy2 >> 1) : yy2) * SW + (UP ? (xx2 >> 1) : xx2)) : 0;
    float* tp2 = tile + ly2 * 20 + lx2;

    float acc[CO_TILE];
#pragma unroll
    for (int j = 0; j < CO_TILE; ++j) acc[j] = 0.f;
    const float* wbase = wf + (size_t)co0 * CIN * 9;

    for (int ci = 0; ci < CIN; ++ci) {
        bool isP0 = (ci < C0);
        const char* src = isP0 ? bb0 + (size_t)ci * SH * SW * esz0
                               : bb1 + (size_t)(ci - C0) * SH * SW * esz1;
        bool sf = isP0 ? (D0 && f32) : (D1 && f32);
        __syncthreads();
        float v1 = 0.f, v2 = 0.f;
        if (sf) {
            if (in1) v1 = ((const float*)src)[sof1];
            if (in2) v2 = ((const float*)src)[sof2];
        } else {
            if (in1) v1 = bf2f(((const __hip_bfloat16*)src)[sof1]);
            if (in2) v2 = bf2f(((const __hip_bfloat16*)src)[sof2]);
        }
        tp1[0] = v1;
        if (has2) tp2[0] = v2;
        __syncthreads();

        float v[9];
#pragma unroll
        for (int r = 0; r < 3; ++r)
#pragma unroll
            for (int c = 0; c < 3; ++c)
                v[r * 3 + c] = tile[(ty + r) * 20 + tx + c];

        const float* wp = wbase + ci * 9;
#pragma unroll
        for (int j = 0; j < CO_TILE; ++j) {
            const float* w9 = wp + (size_t)j * CIN * 9;
#pragma unroll
            for (int k = 0; k < 9; ++k)
                acc[j] = fmaf(v[k], w9[k], acc[j]);
        }
    }

    const int oy = y0 + ty, ox = x0 + tx;
#pragma unroll
    for (int j = 0; j < CO_TILE; ++j) {
        const int co = co0 + j;
        float val = acc[j];
        if (EPI == 0)      val = fmaxf(val * sb[b * Cout + co], 0.f);
        else if (EPI == 1) val = fmaxf(val + sb[co], 0.f);
        else               val = val + sb[co];
        size_t oidx = (((size_t)b * Cout + co) * H + oy) * W + ox;
        if (DOUT && f32) ((float*)outv)[oidx] = val;
        else ((__hip_bfloat16*)outv)[oidx] = __float2bfloat16(val);
    }
}

// ---------------------------------------------------------------------------
// Launch
// ---------------------------------------------------------------------------
extern "C" void kernel_launch(void* const* d_in, const int* in_sizes, int n_in,
                              void* d_out, int out_size, void* d_ws, size_t ws_size,
                              hipStream_t stream) {
    const void* x     = d_in[0];   const void* enc1  = d_in[1];
    const void* enc2  = d_in[2];   const void* enc3  = d_in[3];
    const void* style = d_in[4];
    const void* w1    = d_in[5];   const void* fcw1  = d_in[6];  const void* fcb1 = d_in[7];
    const void* w2    = d_in[8];   const void* fcw2  = d_in[9];  const void* fcb2 = d_in[10];
    const void* fw1   = d_in[11];  const void* fb1   = d_in[12];
    const void* fw2   = d_in[13];  const void* fb2   = d_in[14];
    char* ws = (char*)d_ws;
    auto gb = [](int n) { return (n + 255) / 256; };

    constexpr size_t REQ = 272629760ULL;  // 4MB + 67MB + 67MB + 134MB

    if (ws_size >= REQ) {
        unsigned short* pkw1 = (unsigned short*)(ws + 0);
        unsigned short* pkw2 = (unsigned short*)(ws + 1179648);
        unsigned short* pkw3 = (unsigned short*)(ws + 1474560);
        unsigned short* pkw4 = (unsigned short*)(ws + 1622016);
        float* s1    = (float*)(ws + 1640448);
        float* s2    = (float*)(ws + 1644544);
        float* fb1f  = (float*)(ws + 1646592);
        float* fb2f  = (float*)(ws + 1646848);
        int*   flag  = (int*)(ws + 1646912);
        unsigned short* buf0 = (unsigned short*)(ws + (4u << 20));              // [B,64,64,512]
        unsigned short* h3   = (unsigned short*)(ws + (4u << 20));              // [B,256,256,64]
        unsigned short* buf1 = (unsigned short*)(ws + (4u << 20) + 67108864u);  // [B,128,128,256]
        unsigned short* buf2 = (unsigned short*)(ws + (4u << 20) + 134217728u); // [B,256,256,128]

        hipLaunchKernelGGL(detect_dtype, dim3(1), dim3(256), 0, stream,
                           (const unsigned short*)style, flag);

        hipLaunchKernelGGL(nchw_to_nhwc, dim3(64, 8, 8),   dim3(256), 0, stream, x,    buf0, 256, 4096,  512, 0,   flag);
        hipLaunchKernelGGL(nchw_to_nhwc, dim3(64, 8, 8),   dim3(256), 0, stream, enc3, buf0, 256, 4096,  512, 256, flag);
        hipLaunchKernelGGL(nchw_to_nhwc, dim3(256, 4, 8),  dim3(256), 0, stream, enc2, buf1, 128, 16384, 256, 128, flag);
        hipLaunchKernelGGL(nchw_to_nhwc, dim3(1024, 2, 8), dim3(256), 0, stream, enc1, buf2, 64,  65536, 128, 64,  flag);

        hipLaunchKernelGGL(pack_w, dim3(gb(73728)), dim3(256), 0, stream, w1,  pkw1, 128, 512, 8, 16, flag);
        hipLaunchKernelGGL(pack_w, dim3(gb(18432)), dim3(256), 0, stream, w2,  pkw2, 64,  256, 4, 8,  flag);
        hipLaunchKernelGGL(pack_w, dim3(gb(9216)),  dim3(256), 0, stream, fw1, pkw3, 64,  128, 4, 4,  flag);
        hipLaunchKernelGGL(pack_w, dim3(gb(1152)),  dim3(256), 0, stream, fw2, pkw4, 3,   64,  1, 2,  flag);

        hipLaunchKernelGGL(style_mod, dim3(4), dim3(256), 0, stream, style, fcw1, fcb1, s1, 8, 128, 256, flag);
        hipLaunchKernelGGL(style_mod, dim3(2), dim3(256), 0, stream, style, fcw2, fcb2, s2, 8, 64, 256, flag);
        hipLaunchKernelGGL(cvt_pad_f32, dim3(1), dim3(256), 0, stream, fb1, fb1f, 64, 64, flag);
        hipLaunchKernelGGL(cvt_pad_f32, dim3(1), dim3(256), 0, stream, fb2, fb2f, 3, 16, flag);

        // L1: buf0 [B,64,64,512] -up2-> buf1 ch0-127 (N split in 2)
        hipLaunchKernelGGL((conv_tile_up<512, 128, 128, 4, 8, 256>),
                           dim3(32, 2, 8), dim3(256), 0, stream, buf0, pkw1, s1, buf1);
        // L2: buf1 [B,128,128,256] -up2-> buf2 ch0-63
        hipLaunchKernelGGL((conv_tile_up<256, 256, 256, 4, 4, 128>),
                           dim3(128, 1, 8), dim3(256), 0, stream, buf1, pkw2, s2, buf2);
        // L3: buf2 [B,256,256,128] -> h3 [B,256,256,64]
        hipLaunchKernelGGL((conv_tile<128, 256, 256, 4, 4, 1, 64>),
                           dim3(256, 1, 8), dim3(256), 0, stream, buf2, pkw3, fb1f, h3, flag);
        // L4: h3 -> d_out NCHW [B,3,256,256] (external dtype)
        hipLaunchKernelGGL((conv_tile<64, 256, 256, 1, 1, 2, 16>),
                           dim3(256, 1, 8), dim3(256), 0, stream, h3, pkw4, fb2f, d_out, flag);
        return;
    }

    // ---- fallback path ----
    float* w1f  = (float*)(ws + 0);
    float* w2f  = (float*)(ws + 2359296);
    float* fw1f = (float*)(ws + 2949120);
    float* fw2f = (float*)(ws + 3244032);
    float* s1   = (float*)(ws + 3250944);
    float* s2   = (float*)(ws + 3255040);
    float* fb1f = (float*)(ws + 3257088);
    float* fb2f = (float*)(ws + 3257344);
    int*   flag = (int*)(ws + 3257360);
    __hip_bfloat16* h1 = (__hip_bfloat16*)(ws + (size_t)(4u << 20));
    __hip_bfloat16* h3 = (__hip_bfloat16*)(ws + (size_t)(4u << 20));
    __hip_bfloat16* h2 = (__hip_bfloat16*)(ws + (size_t)(4u << 20) + 67108864u);

    hipLaunchKernelGGL(detect_dtype, dim3(1), dim3(256), 0, stream,
                       (const unsigned short*)style, flag);
    hipLaunchKernelGGL(cvt_pad_f32, dim3(gb(589824)), dim3(256), 0, stream, w1, w1f, 589824, 589824, flag);
    hipLaunchKernelGGL(cvt_pad_f32, dim3(gb(147456)), dim3(256), 0, stream, w2, w2f, 147456, 147456, flag);
    hipLaunchKernelGGL(cvt_pad_f32, dim3(gb(73728)),  dim3(256), 0, stream, fw1, fw1f, 73728, 73728, flag);
    hipLaunchKernelGGL(cvt_pad_f32, dim3(gb(1728)),   dim3(256), 0, stream, fw2, fw2f, 1728, 1728, flag);
    hipLaunchKernelGGL(cvt_pad_f32, dim3(1), dim3(256), 0, stream, fb1, fb1f, 64, 64, flag);
    hipLaunchKernelGGL(cvt_pad_f32, dim3(1), dim3(256), 0, stream, fb2, fb2f, 3, 3, flag);
    hipLaunchKernelGGL(style_mod, dim3(4), dim3(256), 0, stream, style, fcw1, fcb1, s1, 8, 128, 256, flag);
    hipLaunchKernelGGL(style_mod, dim3(2), dim3(256), 0, stream, style, fcw2, fcb2, s2, 8, 64, 256, flag);

    hipLaunchKernelGGL((conv3x3<512, 256, 128, 128, true, 8, 0, true, true, false>),
                       dim3(64, 16, 8), dim3(256), 0, stream, x, enc3, w1f, s1, h1, 128, flag);
    hipLaunchKernelGGL((conv3x3<256, 128, 256, 256, true, 8, 0, false, true, false>),
                       dim3(256, 8, 8), dim3(256), 0, stream, h1, enc2, w2f, s2, h2, 64, flag);
    hipLaunchKernelGGL((conv3x3<128, 64, 256, 256, false, 8, 1, false, true, false>),
                       dim3(256, 8, 8), dim3(256), 0, stream, h2, enc1, fw1f, fb1f, h3, 64, flag);
    hipLaunchKernelGGL((conv3x3<64, 64, 256, 256, false, 3, 2, false, false, true>),
                       dim3(256, 1, 8), dim3(256), 0, stream, h3, h3, fw2f, fb2f, d_out, 3, flag);
}